// Round 1
// baseline (1137.440 us; speedup 1.0000x reference)
//
#include <hip/hip_runtime.h>

#define NN 100000
#define NE 1600000
#define INF 4
#define H 128
#define RR 20
#define OUTF 2

// ---------------- init ----------------
__global__ void k_init_small(float* __restrict__ pooled, int* __restrict__ in_size) {
    int t = threadIdx.x;
    if (t < H) pooled[t] = 0.f;
    if (t == H) *in_size = 0;
}

__global__ void k_init_nodes(const float* __restrict__ x, int* __restrict__ deg,
                             int* __restrict__ cursor, int* __restrict__ in_size) {
    int i = blockIdx.x * 256 + threadIdx.x;
    bool pred = false;
    if (i < NN) {
        deg[i] = 1;          // self-loop
        cursor[i] = 0;
        float x0 = x[(size_t)i * INF + 0];
        float x1 = x[(size_t)i * INF + 1];
        pred = (x0 != 0.f) && (x1 != 0.f);
    }
    unsigned long long m = __ballot(pred);
    if ((threadIdx.x & 63) == 0) {
        int c = __popcll(m);
        if (c) atomicAdd(in_size, c);
    }
}

// ---------------- degree ----------------
__global__ void k_deg(const int* __restrict__ dst, int* __restrict__ deg) {
    int e = blockIdx.x * 256 + threadIdx.x;
    if (e < NE) atomicAdd(&deg[dst[e]], 1);
}

// ---------------- CSR offsets: block sums -> scan -> offsets ----------------
__global__ void k_scan1(const int* __restrict__ deg, int* __restrict__ bsum) {
    __shared__ int sm[256];
    int i = blockIdx.x * 256 + threadIdx.x;
    int v = (i < NN) ? (deg[i] - 1) : 0;   // indegree w/o self-loop = csr entries
    sm[threadIdx.x] = v;
    __syncthreads();
    for (int s = 128; s > 0; s >>= 1) {
        if (threadIdx.x < s) sm[threadIdx.x] += sm[threadIdx.x + s];
        __syncthreads();
    }
    if (threadIdx.x == 0) bsum[blockIdx.x] = sm[0];
}

__global__ void k_scan2(int* __restrict__ bsum, int nb) {
    __shared__ int sm[512];
    int t = threadIdx.x;
    sm[t] = (t < nb) ? bsum[t] : 0;
    __syncthreads();
    for (int off = 1; off < 512; off <<= 1) {
        int v = (t >= off) ? sm[t - off] : 0;
        __syncthreads();
        sm[t] += v;
        __syncthreads();
    }
    if (t < nb) bsum[t] = (t == 0) ? 0 : sm[t - 1];   // exclusive
}

__global__ void k_scan3(const int* __restrict__ deg, const int* __restrict__ bsum,
                        int* __restrict__ csr_off, float* __restrict__ dinv) {
    __shared__ int sm[256];
    int i = blockIdx.x * 256 + threadIdx.x;
    int d = (i < NN) ? deg[i] : 1;
    int v = d - 1;
    sm[threadIdx.x] = v;
    __syncthreads();
    for (int off = 1; off < 256; off <<= 1) {
        int u = (threadIdx.x >= off) ? sm[threadIdx.x - off] : 0;
        __syncthreads();
        sm[threadIdx.x] += u;
        __syncthreads();
    }
    if (i < NN) {
        int excl = bsum[blockIdx.x] + sm[threadIdx.x] - v;
        csr_off[i] = excl;
        if (i == NN - 1) csr_off[NN] = excl + v;
        dinv[i] = rsqrtf((float)d);
    }
}

__global__ void k_fill(const int* __restrict__ src, const int* __restrict__ dst,
                       const int* __restrict__ csr_off, int* __restrict__ cursor,
                       int* __restrict__ csr_src) {
    int e = blockIdx.x * 256 + threadIdx.x;
    if (e < NE) {
        int s = src[e], d = dst[e];
        int p = atomicAdd(&cursor[d], 1);
        csr_src[csr_off[d] + p] = s;
    }
}

// ---------------- layer 1: aggregate x (4 features), then matvec happens in mm1 ----
__global__ void k_aggx(const float* __restrict__ x, const int* __restrict__ csr_off,
                       const int* __restrict__ csr_src, const float* __restrict__ dinv,
                       float* __restrict__ Ax) {
    int i = blockIdx.x * 256 + threadIdx.x;
    if (i >= NN) return;
    int b = csr_off[i], e = csr_off[i + 1];
    float a0 = 0.f, a1 = 0.f, a2 = 0.f, a3 = 0.f;
    for (int j = b; j < e; ++j) {
        int s = csr_src[j];
        float w = dinv[s];
        const float4 xv = *(const float4*)(x + (size_t)s * INF);
        a0 += xv.x * w; a1 += xv.y * w; a2 += xv.z * w; a3 += xv.w * w;
    }
    float di = dinv[i];
    const float4 xi = *(const float4*)(x + (size_t)i * INF);
    a0 = (a0 + xi.x * di) * di;
    a1 = (a1 + xi.y * di) * di;
    a2 = (a2 + xi.z * di) * di;
    a3 = (a3 + xi.w * di) * di;
    *(float4*)(Ax + (size_t)i * INF) = make_float4(a0, a1, a2, a3);
}

// Y = tanh(Ax @ W1 + b1)   [N,4]@[4,128]
__global__ void k_mm1(const float* __restrict__ Ax, const float* __restrict__ W1,
                      const float* __restrict__ b1, float* __restrict__ Y) {
    int tid = threadIdx.x;
    int node = blockIdx.x * 2 + (tid >> 7);
    int f = tid & 127;
    if (node >= NN) return;
    const float4 a = *(const float4*)(Ax + (size_t)node * INF);
    float acc = b1[f];
    acc += a.x * W1[0 * H + f];
    acc += a.y * W1[1 * H + f];
    acc += a.z * W1[2 * H + f];
    acc += a.w * W1[3 * H + f];
    Y[(size_t)node * H + f] = tanhf(acc);
}

// ---------------- layer 2 gather: Z = Agg(Y)  (one wave per node) ----------------
__global__ void k_aggy(const float* __restrict__ Y, const int* __restrict__ csr_off,
                       const int* __restrict__ csr_src, const float* __restrict__ dinv,
                       float* __restrict__ Z) {
    int wid = threadIdx.x >> 6;
    int lane = threadIdx.x & 63;
    int i = blockIdx.x * 4 + wid;
    if (i >= NN) return;
    int b = csr_off[i], e = csr_off[i + 1];
    float a0 = 0.f, a1 = 0.f;
    for (int j = b; j < e; ++j) {
        int s = csr_src[j];
        float w = dinv[s];
        const float2 yv = *(const float2*)(Y + (size_t)s * H + lane * 2);
        a0 += yv.x * w;
        a1 += yv.y * w;
    }
    float di = dinv[i];
    const float2 yi = *(const float2*)(Y + (size_t)i * H + lane * 2);
    a0 = (a0 + yi.x * di) * di;
    a1 = (a1 + yi.y * di) * di;
    *(float2*)(Z + (size_t)i * H + lane * 2) = make_float2(a0, a1);
}

// ---------------- O = tanh(Z @ W2 + b2), fused mean-pool accumulation ------------
// block: 256 threads, 64 nodes staged transposed in LDS; wave w computes features
// [32w, 32w+32) for all 64 nodes (lane = node). W2 via scalar loads (uniform addr).
__global__ void __launch_bounds__(256) k_mm2pool(
    const float* __restrict__ Z, const float* __restrict__ W2,
    const float* __restrict__ b2, float* __restrict__ pooled) {
    __shared__ float zt[H][65];   // [k][node], padded: conflict-free both ways
    int tid = threadIdx.x;
    int nbase = blockIdx.x * 64;
    #pragma unroll
    for (int rep = 0; rep < 32; ++rep) {
        int flat = rep * 256 + tid;     // 8192 = 64*128
        int node = flat >> 7;
        int k = flat & 127;
        int gi = nbase + node;
        float v = (gi < NN) ? Z[(size_t)gi * H + k] : 0.f;
        zt[k][node] = v;
    }
    __syncthreads();

    int wid = tid >> 6, lane = tid & 63;
    int fbase = __builtin_amdgcn_readfirstlane(wid * 32);   // force SGPR path for W2
    const float* w2base = W2 + fbase;

    float acc[32];
    #pragma unroll
    for (int ff = 0; ff < 32; ++ff) acc[ff] = b2[fbase + ff];

    for (int k = 0; k < H; ++k) {
        float zv = zt[k][lane];
        const float* wr = w2base + (size_t)k * H;
        #pragma unroll
        for (int ff = 0; ff < 32; ++ff) acc[ff] += zv * wr[ff];
    }

    bool valid = (nbase + lane) < NN;
    #pragma unroll
    for (int ff = 0; ff < 32; ++ff) {
        float t = valid ? tanhf(acc[ff]) : 0.f;
        #pragma unroll
        for (int s = 32; s > 0; s >>= 1) t += __shfl_xor(t, s, 64);
        if (lane == 0) atomicAdd(&pooled[fbase + ff], t);
    }
}

// ---------------- final: vel = (pooled/N) @ Wfc + bfc, mask by in_size ----------
__global__ void k_final(const float* __restrict__ pooled, const float* __restrict__ Wfc,
                        const float* __restrict__ bfc, const int* __restrict__ in_size,
                        float* __restrict__ out) {
    int t = threadIdx.x;
    if (t >= RR * OUTF) return;
    const float invn = 1.0f / (float)NN;
    float a = bfc[t];
    for (int k = 0; k < H; ++k) a += (pooled[k] * invn) * Wfc[k * (RR * OUTF) + t];
    int r = t >> 1;
    out[t] = (r < *in_size) ? a : 0.f;
}

extern "C" void kernel_launch(void* const* d_in, const int* in_sizes, int n_in,
                              void* d_out, int out_size, void* d_ws, size_t ws_size,
                              hipStream_t stream) {
    const float* x   = (const float*)d_in[0];
    const int*   ei  = (const int*)d_in[1];     // [2, E]
    const float* W1  = (const float*)d_in[3];
    const float* b1  = (const float*)d_in[4];
    const float* W2  = (const float*)d_in[5];
    const float* b2  = (const float*)d_in[6];
    const float* Wfc = (const float*)d_in[7];
    const float* bfc = (const float*)d_in[8];
    float* out = (float*)d_out;

    const int* srcp = ei;
    const int* dstp = ei + NE;

    // workspace layout (512B aligned chunks)
    char* ws = (char*)d_ws;
    size_t off = 0;
    auto alloc = [&](size_t bytes) { void* p = ws + off; off += (bytes + 511) & ~(size_t)511; return p; };
    int*   deg     = (int*)alloc((size_t)NN * 4);
    float* dinv    = (float*)alloc((size_t)NN * 4);
    int*   csr_off = (int*)alloc(((size_t)NN + 1) * 4);
    int*   cursor  = (int*)alloc((size_t)NN * 4);
    int*   bsum    = (int*)alloc(1024 * 4);
    int*   csr_src = (int*)alloc((size_t)NE * 4);
    float* Ax      = (float*)alloc((size_t)NN * INF * 4);
    float* Y       = (float*)alloc((size_t)NN * H * 4);
    float* Z       = (float*)alloc((size_t)NN * H * 4);
    float* pooled  = (float*)alloc(H * 4);
    int*   in_size = (int*)alloc(64);
    (void)off; (void)ws_size; (void)in_sizes; (void)n_in; (void)out_size;

    const int nbN = (NN + 255) / 256;        // 391
    const int nbE = (NE + 255) / 256;        // 6250

    k_init_small<<<1, 256, 0, stream>>>(pooled, in_size);
    k_init_nodes<<<nbN, 256, 0, stream>>>(x, deg, cursor, in_size);
    k_deg<<<nbE, 256, 0, stream>>>(dstp, deg);
    k_scan1<<<nbN, 256, 0, stream>>>(deg, bsum);
    k_scan2<<<1, 512, 0, stream>>>(bsum, nbN);
    k_scan3<<<nbN, 256, 0, stream>>>(deg, bsum, csr_off, dinv);
    k_fill<<<nbE, 256, 0, stream>>>(srcp, dstp, csr_off, cursor, csr_src);
    k_aggx<<<nbN, 256, 0, stream>>>(x, csr_off, csr_src, dinv, Ax);
    k_mm1<<<(NN + 1) / 2, 256, 0, stream>>>(Ax, W1, b1, Y);
    k_aggy<<<(NN + 3) / 4, 256, 0, stream>>>(Y, csr_off, csr_src, dinv, Z);
    k_mm2pool<<<(NN + 63) / 64, 256, 0, stream>>>(Z, W2, b2, pooled);
    k_final<<<1, 64, 0, stream>>>(pooled, Wfc, bfc, in_size, out);
}

// Round 3
// 563.051 us; speedup vs baseline: 2.0201x; 2.0201x over previous
//
#include <hip/hip_runtime.h>

#define NN 100000
#define NE 1600000
#define INF 4
#define H 128
#define RR 20
#define OUTF 2

// ---------------- init ----------------
__global__ void k_init_small(float* __restrict__ pooled, int* __restrict__ in_size) {
    int t = threadIdx.x;
    if (t < H) pooled[t] = 0.f;
    if (t == H) *in_size = 0;
}

__global__ void k_init_nodes(const float* __restrict__ x, int* __restrict__ deg,
                             int* __restrict__ cursor, int* __restrict__ in_size) {
    int i = blockIdx.x * 256 + threadIdx.x;
    bool pred = false;
    if (i < NN) {
        deg[i] = 1;          // self-loop
        cursor[i] = 0;
        float x0 = x[(size_t)i * INF + 0];
        float x1 = x[(size_t)i * INF + 1];
        pred = (x0 != 0.f) && (x1 != 0.f);
    }
    unsigned long long m = __ballot(pred);
    if ((threadIdx.x & 63) == 0) {
        int c = __popcll(m);
        if (c) atomicAdd(in_size, c);
    }
}

// ---------------- degree ----------------
__global__ void k_deg(const int* __restrict__ dst, int* __restrict__ deg) {
    int e = blockIdx.x * 256 + threadIdx.x;
    if (e < NE) atomicAdd(&deg[dst[e]], 1);
}

// ---------------- CSR offsets: block sums -> scan -> offsets ----------------
__global__ void k_scan1(const int* __restrict__ deg, int* __restrict__ bsum) {
    __shared__ int sm[256];
    int i = blockIdx.x * 256 + threadIdx.x;
    int v = (i < NN) ? (deg[i] - 1) : 0;   // indegree w/o self-loop = csr entries
    sm[threadIdx.x] = v;
    __syncthreads();
    for (int s = 128; s > 0; s >>= 1) {
        if (threadIdx.x < s) sm[threadIdx.x] += sm[threadIdx.x + s];
        __syncthreads();
    }
    if (threadIdx.x == 0) bsum[blockIdx.x] = sm[0];
}

__global__ void k_scan2(int* __restrict__ bsum, int nb) {
    __shared__ int sm[512];
    int t = threadIdx.x;
    sm[t] = (t < nb) ? bsum[t] : 0;
    __syncthreads();
    for (int off = 1; off < 512; off <<= 1) {
        int v = (t >= off) ? sm[t - off] : 0;
        __syncthreads();
        sm[t] += v;
        __syncthreads();
    }
    if (t < nb) bsum[t] = (t == 0) ? 0 : sm[t - 1];   // exclusive
}

__global__ void k_scan3(const int* __restrict__ deg, const int* __restrict__ bsum,
                        int* __restrict__ csr_off, float* __restrict__ dinv) {
    __shared__ int sm[256];
    int i = blockIdx.x * 256 + threadIdx.x;
    int d = (i < NN) ? deg[i] : 1;
    int v = d - 1;
    sm[threadIdx.x] = v;
    __syncthreads();
    for (int off = 1; off < 256; off <<= 1) {
        int u = (threadIdx.x >= off) ? sm[threadIdx.x - off] : 0;
        __syncthreads();
        sm[threadIdx.x] += u;
        __syncthreads();
    }
    if (i < NN) {
        int excl = bsum[blockIdx.x] + sm[threadIdx.x] - v;
        csr_off[i] = excl;
        if (i == NN - 1) csr_off[NN] = excl + v;
        dinv[i] = rsqrtf((float)d);
    }
}

__global__ void k_fill(const int* __restrict__ src, const int* __restrict__ dst,
                       const int* __restrict__ csr_off, int* __restrict__ cursor,
                       int* __restrict__ csr_src) {
    int e = blockIdx.x * 256 + threadIdx.x;
    if (e < NE) {
        int s = src[e], d = dst[e];
        int p = atomicAdd(&cursor[d], 1);
        csr_src[csr_off[d] + p] = s;
    }
}

// ---------------- layer 1: aggregate x (4 features) ----------------
__global__ void k_aggx(const float* __restrict__ x, const int* __restrict__ csr_off,
                       const int* __restrict__ csr_src, const float* __restrict__ dinv,
                       float* __restrict__ Ax) {
    int i = blockIdx.x * 256 + threadIdx.x;
    if (i >= NN) return;
    int b = csr_off[i], e = csr_off[i + 1];
    float a0 = 0.f, a1 = 0.f, a2 = 0.f, a3 = 0.f;
    for (int j = b; j < e; ++j) {
        int s = csr_src[j];
        float w = dinv[s];
        const float4 xv = *(const float4*)(x + (size_t)s * INF);
        a0 += xv.x * w; a1 += xv.y * w; a2 += xv.z * w; a3 += xv.w * w;
    }
    float di = dinv[i];
    const float4 xi = *(const float4*)(x + (size_t)i * INF);
    a0 = (a0 + xi.x * di) * di;
    a1 = (a1 + xi.y * di) * di;
    a2 = (a2 + xi.z * di) * di;
    a3 = (a3 + xi.w * di) * di;
    *(float4*)(Ax + (size_t)i * INF) = make_float4(a0, a1, a2, a3);
}

// Y = tanh(Ax @ W1 + b1)   [N,4]@[4,128]
__global__ void k_mm1(const float* __restrict__ Ax, const float* __restrict__ W1,
                      const float* __restrict__ b1, float* __restrict__ Y) {
    int tid = threadIdx.x;
    int node = blockIdx.x * 2 + (tid >> 7);
    int f = tid & 127;
    if (node >= NN) return;
    const float4 a = *(const float4*)(Ax + (size_t)node * INF);
    float acc = b1[f];
    acc += a.x * W1[0 * H + f];
    acc += a.y * W1[1 * H + f];
    acc += a.z * W1[2 * H + f];
    acc += a.w * W1[3 * H + f];
    Y[(size_t)node * H + f] = tanhf(acc);
}

// ---------------- layer 2 gather: Z = Agg(Y)  (one wave per node) ----------------
__global__ void k_aggy(const float* __restrict__ Y, const int* __restrict__ csr_off,
                       const int* __restrict__ csr_src, const float* __restrict__ dinv,
                       float* __restrict__ Z) {
    int wid = threadIdx.x >> 6;
    int lane = threadIdx.x & 63;
    int i = blockIdx.x * 4 + wid;
    if (i >= NN) return;
    int b = csr_off[i], e = csr_off[i + 1];
    float a0 = 0.f, a1 = 0.f;
    for (int j = b; j < e; ++j) {
        int s = csr_src[j];
        float w = dinv[s];
        const float2 yv = *(const float2*)(Y + (size_t)s * H + lane * 2);
        a0 += yv.x * w;
        a1 += yv.y * w;
    }
    float di = dinv[i];
    const float2 yi = *(const float2*)(Y + (size_t)i * H + lane * 2);
    a0 = (a0 + yi.x * di) * di;
    a1 = (a1 + yi.y * di) * di;
    *(float2*)(Z + (size_t)i * H + lane * 2) = make_float2(a0, a1);
}

// ---------------- O = tanh(Z @ W2 + b2), fused mean-pool accumulation ------------
// LDS-resident GEMM. Block = 256 thr (4 waves). Each block owns a 64-feature half
// of W2 (32 KB LDS) and grid-strides over 64-node tiles of Z (32 KB LDS, transposed,
// XOR-swizzled). Per lane: 4 nodes x 4 feats register tile -> per k-step:
// 2x ds_read_b128 + 16 v_fma (VALU-bound, all inner-loop traffic in LDS).
// zt swizzle: col' = col ^ (((k>>2)&15)<<2) -> staging writes 2-way (free),
// reads conflict-free, b128 alignment preserved (XOR is 4-float aligned).
__global__ void __launch_bounds__(256) k_mm2pool(
    const float* __restrict__ Z, const float* __restrict__ W2,
    const float* __restrict__ b2, float* __restrict__ pooled) {
    __shared__ float w2s[H][64];   // [k][feat-in-half], 32 KB
    __shared__ float zt[H][64];    // [k][node^swz],     32 KB

    int tid = threadIdx.x;
    int fhalf = blockIdx.x & 1;                 // feature half: [fhalf*64, fhalf*64+64)

    // stage W2 half once per block: 8192 floats, coalesced float4
    #pragma unroll
    for (int rep = 0; rep < 8; ++rep) {
        int flat = rep * 256 + tid;
        int k = flat >> 4;
        int j4 = (flat & 15) * 4;
        float4 v = *(const float4*)(W2 + (size_t)k * H + fhalf * 64 + j4);
        *(float4*)(&w2s[k][j4]) = v;
    }

    int wid = tid >> 6, lane = tid & 63;
    int ng = lane & 15, fg = lane >> 4;
    int fbase = fhalf * 64 + wid * 16 + fg * 4;  // 4 feats per lane
    int fcol  = wid * 16 + fg * 4;               // within-half column

    float bias[4];
    #pragma unroll
    for (int b = 0; b < 4; ++b) bias[b] = b2[fbase + b];

    float pool[4] = {0.f, 0.f, 0.f, 0.f};

    const int ntiles = (NN + 63) >> 6;           // 1563
    for (int tile = blockIdx.x >> 1; tile < ntiles; tile += (int)(gridDim.x >> 1)) {
        __syncthreads();                          // zt reuse (also covers W2 staging, iter 0)
        int nbase = tile << 6;
        // stage 64-node tile, transposed into zt with XOR swizzle
        #pragma unroll
        for (int rep = 0; rep < 8; ++rep) {
            int flat = rep * 256 + tid;
            int node = flat >> 5;                 // 0..63
            int k4 = (flat & 31) * 4;             // 0..124
            int gi = nbase + node;
            float4 v = make_float4(0.f, 0.f, 0.f, 0.f);
            if (gi < NN) v = *(const float4*)(Z + (size_t)gi * H + k4);
            #pragma unroll
            for (int i = 0; i < 4; ++i) {
                int k = k4 + i;
                int col = node ^ (((k >> 2) & 15) << 2);
                zt[k][col] = (&v.x)[i];
            }
        }
        __syncthreads();

        float acc[4][4];
        #pragma unroll
        for (int a = 0; a < 4; ++a)
            #pragma unroll
            for (int b = 0; b < 4; ++b) acc[a][b] = bias[b];

        #pragma unroll 4
        for (int k = 0; k < H; ++k) {
            int zc = (ng * 4) ^ (((k >> 2) & 15) << 2);
            const float4 zv = *(const float4*)(&zt[k][zc]);
            const float4 wv = *(const float4*)(&w2s[k][fcol]);
            acc[0][0] += zv.x * wv.x; acc[0][1] += zv.x * wv.y; acc[0][2] += zv.x * wv.z; acc[0][3] += zv.x * wv.w;
            acc[1][0] += zv.y * wv.x; acc[1][1] += zv.y * wv.y; acc[1][2] += zv.y * wv.z; acc[1][3] += zv.y * wv.w;
            acc[2][0] += zv.z * wv.x; acc[2][1] += zv.z * wv.y; acc[2][2] += zv.z * wv.z; acc[2][3] += zv.z * wv.w;
            acc[3][0] += zv.w * wv.x; acc[3][1] += zv.w * wv.y; acc[3][2] += zv.w * wv.z; acc[3][3] += zv.w * wv.w;
        }

        // tanh + masked pool accumulation (invalid nodes contribute 0)
        #pragma unroll
        for (int a = 0; a < 4; ++a) {
            bool valid = (nbase + ng * 4 + a) < NN;
            #pragma unroll
            for (int b = 0; b < 4; ++b) {
                pool[b] += valid ? tanhf(acc[a][b]) : 0.f;
            }
        }
    }

    // reduce pool over the 16 ng-lanes sharing the same features
    #pragma unroll
    for (int b = 0; b < 4; ++b) {
        float t = pool[b];
        t += __shfl_xor(t, 1, 64);
        t += __shfl_xor(t, 2, 64);
        t += __shfl_xor(t, 4, 64);
        t += __shfl_xor(t, 8, 64);
        if (ng == 0) atomicAdd(&pooled[fbase + b], t);
    }
}

// ---------------- final: vel = (pooled/N) @ Wfc + bfc, mask by in_size ----------
__global__ void k_final(const float* __restrict__ pooled, const float* __restrict__ Wfc,
                        const float* __restrict__ bfc, const int* __restrict__ in_size,
                        float* __restrict__ out) {
    int t = threadIdx.x;
    if (t >= RR * OUTF) return;
    const float invn = 1.0f / (float)NN;
    float a = bfc[t];
    for (int k = 0; k < H; ++k) a += (pooled[k] * invn) * Wfc[k * (RR * OUTF) + t];
    int r = t >> 1;
    out[t] = (r < *in_size) ? a : 0.f;
}

extern "C" void kernel_launch(void* const* d_in, const int* in_sizes, int n_in,
                              void* d_out, int out_size, void* d_ws, size_t ws_size,
                              hipStream_t stream) {
    const float* x   = (const float*)d_in[0];
    const int*   ei  = (const int*)d_in[1];     // [2, E]
    const float* W1  = (const float*)d_in[3];
    const float* b1  = (const float*)d_in[4];
    const float* W2  = (const float*)d_in[5];
    const float* b2  = (const float*)d_in[6];
    const float* Wfc = (const float*)d_in[7];
    const float* bfc = (const float*)d_in[8];
    float* out = (float*)d_out;

    const int* srcp = ei;
    const int* dstp = ei + NE;

    // workspace layout (512B aligned chunks)
    char* ws = (char*)d_ws;
    size_t off = 0;
    auto alloc = [&](size_t bytes) { void* p = ws + off; off += (bytes + 511) & ~(size_t)511; return p; };
    int*   deg     = (int*)alloc((size_t)NN * 4);
    float* dinv    = (float*)alloc((size_t)NN * 4);
    int*   csr_off = (int*)alloc(((size_t)NN + 1) * 4);
    int*   cursor  = (int*)alloc((size_t)NN * 4);
    int*   bsum    = (int*)alloc(1024 * 4);
    int*   csr_src = (int*)alloc((size_t)NE * 4);
    float* Ax      = (float*)alloc((size_t)NN * INF * 4);
    float* Y       = (float*)alloc((size_t)NN * H * 4);
    float* Z       = (float*)alloc((size_t)NN * H * 4);
    float* pooled  = (float*)alloc(H * 4);
    int*   in_size = (int*)alloc(64);
    (void)off; (void)ws_size; (void)in_sizes; (void)n_in; (void)out_size;

    const int nbN = (NN + 255) / 256;        // 391
    const int nbE = (NE + 255) / 256;        // 6250

    k_init_small<<<1, 256, 0, stream>>>(pooled, in_size);
    k_init_nodes<<<nbN, 256, 0, stream>>>(x, deg, cursor, in_size);
    k_deg<<<nbE, 256, 0, stream>>>(dstp, deg);
    k_scan1<<<nbN, 256, 0, stream>>>(deg, bsum);
    k_scan2<<<1, 512, 0, stream>>>(bsum, nbN);
    k_scan3<<<nbN, 256, 0, stream>>>(deg, bsum, csr_off, dinv);
    k_fill<<<nbE, 256, 0, stream>>>(srcp, dstp, csr_off, cursor, csr_src);
    k_aggx<<<nbN, 256, 0, stream>>>(x, csr_off, csr_src, dinv, Ax);
    k_mm1<<<(NN + 1) / 2, 256, 0, stream>>>(Ax, W1, b1, Y);
    k_aggy<<<(NN + 3) / 4, 256, 0, stream>>>(Y, csr_off, csr_src, dinv, Z);
    k_mm2pool<<<512, 256, 0, stream>>>(Z, W2, b2, pooled);
    k_final<<<1, 64, 0, stream>>>(pooled, Wfc, bfc, in_size, out);
}

// Round 4
// 501.422 us; speedup vs baseline: 2.2684x; 1.1229x over previous
//
#include <hip/hip_runtime.h>

#define NN 100000
#define NE 1600000
#define INF 4
#define H 128
#define RR 20
#define OUTF 2

typedef unsigned int uint32;

// round-to-nearest-even bf16 pack: x -> low 16, y -> high 16
__device__ inline uint32 pack_bf16(float x, float y) {
    uint32 ux = __float_as_uint(x);
    uint32 uy = __float_as_uint(y);
    ux = (ux + 0x7fffu + ((ux >> 16) & 1u)) >> 16;
    uy = (uy + 0x7fffu + ((uy >> 16) & 1u)) & 0xffff0000u;
    return ux | uy;
}

// ---------------- init ----------------
__global__ void k_init_small(float* __restrict__ pooled, int* __restrict__ in_size) {
    int t = threadIdx.x;
    if (t < H) pooled[t] = 0.f;
    if (t == H) *in_size = 0;
}

__global__ void k_init_nodes(const float* __restrict__ x, int* __restrict__ deg,
                             int* __restrict__ cursor, int* __restrict__ in_size) {
    int i = blockIdx.x * 256 + threadIdx.x;
    bool pred = false;
    if (i < NN) {
        deg[i] = 1;          // self-loop
        cursor[i] = 0;
        float x0 = x[(size_t)i * INF + 0];
        float x1 = x[(size_t)i * INF + 1];
        pred = (x0 != 0.f) && (x1 != 0.f);
    }
    unsigned long long m = __ballot(pred);
    if ((threadIdx.x & 63) == 0) {
        int c = __popcll(m);
        if (c) atomicAdd(in_size, c);
    }
}

// ---------------- degree ----------------
__global__ void k_deg(const int* __restrict__ dst, int* __restrict__ deg) {
    int e = blockIdx.x * 256 + threadIdx.x;
    if (e < NE) atomicAdd(&deg[dst[e]], 1);
}

// ---------------- CSR offsets: block sums -> scan -> offsets ----------------
__global__ void k_scan1(const int* __restrict__ deg, int* __restrict__ bsum) {
    __shared__ int sm[256];
    int i = blockIdx.x * 256 + threadIdx.x;
    int v = (i < NN) ? (deg[i] - 1) : 0;   // indegree w/o self-loop = csr entries
    sm[threadIdx.x] = v;
    __syncthreads();
    for (int s = 128; s > 0; s >>= 1) {
        if (threadIdx.x < s) sm[threadIdx.x] += sm[threadIdx.x + s];
        __syncthreads();
    }
    if (threadIdx.x == 0) bsum[blockIdx.x] = sm[0];
}

__global__ void k_scan2(int* __restrict__ bsum, int nb) {
    __shared__ int sm[512];
    int t = threadIdx.x;
    sm[t] = (t < nb) ? bsum[t] : 0;
    __syncthreads();
    for (int off = 1; off < 512; off <<= 1) {
        int v = (t >= off) ? sm[t - off] : 0;
        __syncthreads();
        sm[t] += v;
        __syncthreads();
    }
    if (t < nb) bsum[t] = (t == 0) ? 0 : sm[t - 1];   // exclusive
}

__global__ void k_scan3(const int* __restrict__ deg, const int* __restrict__ bsum,
                        int* __restrict__ csr_off, float* __restrict__ dinv) {
    __shared__ int sm[256];
    int i = blockIdx.x * 256 + threadIdx.x;
    int d = (i < NN) ? deg[i] : 1;
    int v = d - 1;
    sm[threadIdx.x] = v;
    __syncthreads();
    for (int off = 1; off < 256; off <<= 1) {
        int u = (threadIdx.x >= off) ? sm[threadIdx.x - off] : 0;
        __syncthreads();
        sm[threadIdx.x] += u;
        __syncthreads();
    }
    if (i < NN) {
        int excl = bsum[blockIdx.x] + sm[threadIdx.x] - v;
        csr_off[i] = excl;
        if (i == NN - 1) csr_off[NN] = excl + v;
        dinv[i] = rsqrtf((float)d);
    }
}

__global__ void k_fill(const int* __restrict__ src, const int* __restrict__ dst,
                       const int* __restrict__ csr_off, int* __restrict__ cursor,
                       int* __restrict__ csr_src) {
    int e = blockIdx.x * 256 + threadIdx.x;
    if (e < NE) {
        int s = src[e], d = dst[e];
        int p = atomicAdd(&cursor[d], 1);
        csr_src[csr_off[d] + p] = s;
    }
}

// ---------------- layer 1: aggregate x (4 features) ----------------
__global__ void k_aggx(const float* __restrict__ x, const int* __restrict__ csr_off,
                       const int* __restrict__ csr_src, const float* __restrict__ dinv,
                       float* __restrict__ Ax) {
    int i = blockIdx.x * 256 + threadIdx.x;
    if (i >= NN) return;
    int b = csr_off[i], e = csr_off[i + 1];
    float a0 = 0.f, a1 = 0.f, a2 = 0.f, a3 = 0.f;
    for (int j = b; j < e; ++j) {
        int s = csr_src[j];
        float w = dinv[s];
        const float4 xv = *(const float4*)(x + (size_t)s * INF);
        a0 += xv.x * w; a1 += xv.y * w; a2 += xv.z * w; a3 += xv.w * w;
    }
    float di = dinv[i];
    const float4 xi = *(const float4*)(x + (size_t)i * INF);
    a0 = (a0 + xi.x * di) * di;
    a1 = (a1 + xi.y * di) * di;
    a2 = (a2 + xi.z * di) * di;
    a3 = (a3 + xi.w * di) * di;
    *(float4*)(Ax + (size_t)i * INF) = make_float4(a0, a1, a2, a3);
}

// Yp = pack_bf16( tanh(Ax @ W1 + b1) * dinv )   [N, 64] uint (2 bf16 feats/lane)
// one wave per node; lane covers features 2l, 2l+1 -> 256B coalesced row store
__global__ void k_mm1(const float* __restrict__ Ax, const float* __restrict__ W1,
                      const float* __restrict__ b1, const float* __restrict__ dinv,
                      uint32* __restrict__ Yp) {
    int tid = threadIdx.x;
    int wid = tid >> 6, lane = tid & 63;
    int node = blockIdx.x * 4 + wid;
    if (node >= NN) return;
    const float4 a = *(const float4*)(Ax + (size_t)node * INF);
    float di = dinv[node];
    int f0 = lane * 2;
    const float2 w0 = *(const float2*)(W1 + 0 * H + f0);
    const float2 w1 = *(const float2*)(W1 + 1 * H + f0);
    const float2 w2 = *(const float2*)(W1 + 2 * H + f0);
    const float2 w3 = *(const float2*)(W1 + 3 * H + f0);
    const float2 bb = *(const float2*)(b1 + f0);
    float acc0 = bb.x + a.x * w0.x + a.y * w1.x + a.z * w2.x + a.w * w3.x;
    float acc1 = bb.y + a.x * w0.y + a.y * w1.y + a.z * w2.y + a.w * w3.y;
    Yp[(size_t)node * 64 + lane] = pack_bf16(tanhf(acc0) * di, tanhf(acc1) * di);
}

// ---------------- layer 2 gather: Z = dinv[i] * (sum Yp[s] + Yp[i]) -------------
// one wave per node; per edge: one coalesced 256B row read (uint = 2 bf16 / lane).
// edge loop unrolled x2 for memory-level parallelism.
__global__ void k_aggy(const uint32* __restrict__ Yp, const int* __restrict__ csr_off,
                       const int* __restrict__ csr_src, const float* __restrict__ dinv,
                       float* __restrict__ Z) {
    int wid = threadIdx.x >> 6;
    int lane = threadIdx.x & 63;
    int i = blockIdx.x * 4 + wid;
    if (i >= NN) return;
    int b = csr_off[i], e = csr_off[i + 1];
    float a0 = 0.f, a1 = 0.f;
    int j = b;
    for (; j + 2 <= e; j += 2) {
        int s0 = csr_src[j];
        int s1 = csr_src[j + 1];
        uint32 v0 = Yp[(size_t)s0 * 64 + lane];
        uint32 v1 = Yp[(size_t)s1 * 64 + lane];
        a0 += __uint_as_float(v0 << 16);
        a1 += __uint_as_float(v0 & 0xffff0000u);
        a0 += __uint_as_float(v1 << 16);
        a1 += __uint_as_float(v1 & 0xffff0000u);
    }
    if (j < e) {
        uint32 v = Yp[(size_t)csr_src[j] * 64 + lane];
        a0 += __uint_as_float(v << 16);
        a1 += __uint_as_float(v & 0xffff0000u);
    }
    uint32 vi = Yp[(size_t)i * 64 + lane];
    a0 += __uint_as_float(vi << 16);
    a1 += __uint_as_float(vi & 0xffff0000u);
    float di = dinv[i];
    *(float2*)(Z + (size_t)i * H + lane * 2) = make_float2(a0 * di, a1 * di);
}

// ---------------- O = tanh(Z @ W2 + b2), fused mean-pool accumulation ------------
__global__ void __launch_bounds__(256) k_mm2pool(
    const float* __restrict__ Z, const float* __restrict__ W2,
    const float* __restrict__ b2, float* __restrict__ pooled) {
    __shared__ float w2s[H][64];   // [k][feat-in-half], 32 KB
    __shared__ float zt[H][64];    // [k][node^swz],     32 KB

    int tid = threadIdx.x;
    int fhalf = blockIdx.x & 1;                 // feature half: [fhalf*64, fhalf*64+64)

    // stage W2 half once per block: 8192 floats, coalesced float4
    #pragma unroll
    for (int rep = 0; rep < 8; ++rep) {
        int flat = rep * 256 + tid;
        int k = flat >> 4;
        int j4 = (flat & 15) * 4;
        float4 v = *(const float4*)(W2 + (size_t)k * H + fhalf * 64 + j4);
        *(float4*)(&w2s[k][j4]) = v;
    }

    int wid = tid >> 6, lane = tid & 63;
    int ng = lane & 15, fg = lane >> 4;
    int fbase = fhalf * 64 + wid * 16 + fg * 4;  // 4 feats per lane
    int fcol  = wid * 16 + fg * 4;               // within-half column

    float bias[4];
    #pragma unroll
    for (int b = 0; b < 4; ++b) bias[b] = b2[fbase + b];

    float pool[4] = {0.f, 0.f, 0.f, 0.f};

    const int ntiles = (NN + 63) >> 6;           // 1563
    for (int tile = blockIdx.x >> 1; tile < ntiles; tile += (int)(gridDim.x >> 1)) {
        __syncthreads();                          // zt reuse (also covers W2 staging, iter 0)
        int nbase = tile << 6;
        // stage 64-node tile, transposed into zt with XOR swizzle
        #pragma unroll
        for (int rep = 0; rep < 8; ++rep) {
            int flat = rep * 256 + tid;
            int node = flat >> 5;                 // 0..63
            int k4 = (flat & 31) * 4;             // 0..124
            int gi = nbase + node;
            float4 v = make_float4(0.f, 0.f, 0.f, 0.f);
            if (gi < NN) v = *(const float4*)(Z + (size_t)gi * H + k4);
            #pragma unroll
            for (int i = 0; i < 4; ++i) {
                int k = k4 + i;
                int col = node ^ (((k >> 2) & 15) << 2);
                zt[k][col] = (&v.x)[i];
            }
        }
        __syncthreads();

        float acc[4][4];
        #pragma unroll
        for (int a = 0; a < 4; ++a)
            #pragma unroll
            for (int b = 0; b < 4; ++b) acc[a][b] = bias[b];

        #pragma unroll 4
        for (int k = 0; k < H; ++k) {
            int zc = (ng * 4) ^ (((k >> 2) & 15) << 2);
            const float4 zv = *(const float4*)(&zt[k][zc]);
            const float4 wv = *(const float4*)(&w2s[k][fcol]);
            acc[0][0] += zv.x * wv.x; acc[0][1] += zv.x * wv.y; acc[0][2] += zv.x * wv.z; acc[0][3] += zv.x * wv.w;
            acc[1][0] += zv.y * wv.x; acc[1][1] += zv.y * wv.y; acc[1][2] += zv.y * wv.z; acc[1][3] += zv.y * wv.w;
            acc[2][0] += zv.z * wv.x; acc[2][1] += zv.z * wv.y; acc[2][2] += zv.z * wv.z; acc[2][3] += zv.z * wv.w;
            acc[3][0] += zv.w * wv.x; acc[3][1] += zv.w * wv.y; acc[3][2] += zv.w * wv.z; acc[3][3] += zv.w * wv.w;
        }

        // tanh + masked pool accumulation (invalid nodes contribute 0)
        #pragma unroll
        for (int a = 0; a < 4; ++a) {
            bool valid = (nbase + ng * 4 + a) < NN;
            #pragma unroll
            for (int b = 0; b < 4; ++b) {
                pool[b] += valid ? tanhf(acc[a][b]) : 0.f;
            }
        }
    }

    // reduce pool over the 16 ng-lanes sharing the same features
    #pragma unroll
    for (int b = 0; b < 4; ++b) {
        float t = pool[b];
        t += __shfl_xor(t, 1, 64);
        t += __shfl_xor(t, 2, 64);
        t += __shfl_xor(t, 4, 64);
        t += __shfl_xor(t, 8, 64);
        if (ng == 0) atomicAdd(&pooled[fbase + b], t);
    }
}

// ---------------- final: vel = (pooled/N) @ Wfc + bfc, mask by in_size ----------
__global__ void k_final(const float* __restrict__ pooled, const float* __restrict__ Wfc,
                        const float* __restrict__ bfc, const int* __restrict__ in_size,
                        float* __restrict__ out) {
    int t = threadIdx.x;
    if (t >= RR * OUTF) return;
    const float invn = 1.0f / (float)NN;
    float a = bfc[t];
    for (int k = 0; k < H; ++k) a += (pooled[k] * invn) * Wfc[k * (RR * OUTF) + t];
    int r = t >> 1;
    out[t] = (r < *in_size) ? a : 0.f;
}

extern "C" void kernel_launch(void* const* d_in, const int* in_sizes, int n_in,
                              void* d_out, int out_size, void* d_ws, size_t ws_size,
                              hipStream_t stream) {
    const float* x   = (const float*)d_in[0];
    const int*   ei  = (const int*)d_in[1];     // [2, E]
    const float* W1  = (const float*)d_in[3];
    const float* b1  = (const float*)d_in[4];
    const float* W2  = (const float*)d_in[5];
    const float* b2  = (const float*)d_in[6];
    const float* Wfc = (const float*)d_in[7];
    const float* bfc = (const float*)d_in[8];
    float* out = (float*)d_out;

    const int* srcp = ei;
    const int* dstp = ei + NE;

    // workspace layout (512B aligned chunks)
    char* ws = (char*)d_ws;
    size_t off = 0;
    auto alloc = [&](size_t bytes) { void* p = ws + off; off += (bytes + 511) & ~(size_t)511; return p; };
    int*   deg     = (int*)alloc((size_t)NN * 4);
    float* dinv    = (float*)alloc((size_t)NN * 4);
    int*   csr_off = (int*)alloc(((size_t)NN + 1) * 4);
    int*   cursor  = (int*)alloc((size_t)NN * 4);
    int*   bsum    = (int*)alloc(1024 * 4);
    int*   csr_src = (int*)alloc((size_t)NE * 4);
    float* Ax      = (float*)alloc((size_t)NN * INF * 4);
    uint32* Yp     = (uint32*)alloc((size_t)NN * 64 * 4);   // packed bf16, premult by dinv
    float* Z       = (float*)alloc((size_t)NN * H * 4);
    float* pooled  = (float*)alloc(H * 4);
    int*   in_size = (int*)alloc(64);
    (void)off; (void)ws_size; (void)in_sizes; (void)n_in; (void)out_size;

    const int nbN = (NN + 255) / 256;        // 391
    const int nbE = (NE + 255) / 256;        // 6250
    const int nbW = (NN + 3) / 4;            // 4 waves (nodes) per block

    k_init_small<<<1, 256, 0, stream>>>(pooled, in_size);
    k_init_nodes<<<nbN, 256, 0, stream>>>(x, deg, cursor, in_size);
    k_deg<<<nbE, 256, 0, stream>>>(dstp, deg);
    k_scan1<<<nbN, 256, 0, stream>>>(deg, bsum);
    k_scan2<<<1, 512, 0, stream>>>(bsum, nbN);
    k_scan3<<<nbN, 256, 0, stream>>>(deg, bsum, csr_off, dinv);
    k_fill<<<nbE, 256, 0, stream>>>(srcp, dstp, csr_off, cursor, csr_src);
    k_aggx<<<nbN, 256, 0, stream>>>(x, csr_off, csr_src, dinv, Ax);
    k_mm1<<<nbW, 256, 0, stream>>>(Ax, W1, b1, dinv, Yp);
    k_aggy<<<nbW, 256, 0, stream>>>(Yp, csr_off, csr_src, dinv, Z);
    k_mm2pool<<<512, 256, 0, stream>>>(Z, W2, b2, pooled);
    k_final<<<1, 64, 0, stream>>>(pooled, Wfc, bfc, in_size, out);
}